// Round 11
// baseline (181.040 us; speedup 1.0000x reference)
//
#include <hip/hip_runtime.h>
#include <cstdint>
#include <cstddef>

typedef __bf16 bf16_t;
typedef __bf16 bf16x8 __attribute__((ext_vector_type(8)));
typedef __bf16 bf16x4 __attribute__((ext_vector_type(4)));
typedef float f32x4 __attribute__((ext_vector_type(4)));

#define N_SEQ 2048
#define BATCH 2
#define EMB   1024
#define HID   1024
#define NHEAD 16
#define HDIM  64
#define NBROW (N_SEQ * BATCH)   /* 4096 GEMM rows (n*B+b) */
#define ATT_SCALE2 (0.03125f * 1.44269504f)  /* 1/sqrt(1024) * log2(e) */

#define EXP2F(x) __builtin_amdgcn_exp2f(x)   /* __exp2f collides with glibc macro */

static __device__ __forceinline__ void async_copy16(const bf16_t* g, bf16_t* l) {
  __builtin_amdgcn_global_load_lds((const __attribute__((address_space(1))) void*)g,
                                   (__attribute__((address_space(3))) void*)l,
                                   16, 0, 0);
}

// ---------------- fused prep: convert x + transpose both weights -----------
__global__ __launch_bounds__(256) void prep_kernel(
    const float* __restrict__ x, const float* __restrict__ Wp,
    const float* __restrict__ Wo, bf16_t* __restrict__ Xb,
    bf16_t* __restrict__ Wpt, bf16_t* __restrict__ Wot) {
  int bid = blockIdx.x;
  if (bid < 4096) {
    int i = (bid * 256 + threadIdx.x) * 4;
    float4 v = *(const float4*)(x + i);
    bf16x4 o;
    o[0] = (bf16_t)v.x; o[1] = (bf16_t)v.y; o[2] = (bf16_t)v.z; o[3] = (bf16_t)v.w;
    *(bf16x4*)(Xb + i) = o;
    return;
  }
  __shared__ float tile[32][33];
  const float* in; bf16_t* out; int R, C, bx;
  if (bid < 4096 + 3072) { bx = bid - 4096; in = Wp; out = Wpt; R = 1024; C = 3072; }
  else                   { bx = bid - 7168; in = Wo; out = Wot; R = 1024; C = 1024; }
  int gx = C / 32;
  int bc = (bx % gx) * 32, br = (bx / gx) * 32;
  int tx = threadIdx.x & 31, ty = threadIdx.x >> 5;   // 32 x 8
  #pragma unroll
  for (int i = 0; i < 32; i += 8)
    tile[ty + i][tx] = in[(size_t)(br + ty + i) * C + bc + tx];
  __syncthreads();
  #pragma unroll
  for (int i = 0; i < 32; i += 8)
    out[(size_t)(bc + ty + i) * R + br + tx] = (bf16_t)tile[tx][ty + i];
}

// ------- V transpose: Pj[n*B+b][2048 + h*64 + d] -> Vt[(b,h)][d][n] --------
__global__ void vt_transpose_kernel(const bf16_t* __restrict__ Pj,
                                    bf16_t* __restrict__ Vt) {
  __shared__ bf16_t tile[32][33];
  int tx = threadIdx.x & 31, ty = threadIdx.x >> 5;
  int n0 = blockIdx.x * 32, d0 = blockIdx.y * 32;
  int bh = blockIdx.z;
  int h = bh & 15, b = bh >> 4;
  const int PJP = 3 * HID;
  #pragma unroll
  for (int i = 0; i < 32; i += 8)
    tile[ty + i][tx] = Pj[(size_t)((n0 + ty + i) * BATCH + b) * PJP + 2 * HID + h * HDIM + d0 + tx];
  __syncthreads();
  #pragma unroll
  for (int i = 0; i < 32; i += 8)
    Vt[(size_t)(bh * HDIM + d0 + ty + i) * N_SEQ + n0 + tx] = tile[tx][ty + i];
}

// ---------------- pipelined GEMM: C = A * Bt^T + bias ----------------------
// BK=32 double-buffer, ONE barrier per K-iter: next tile's loads are issued
// right after the barrier, so the barrier's implicit vmcnt(0) drain hits
// loads that are a full compute phase (~200+ cyc) old -- covers L2 latency
// -- while LDS stays small (QKV 24 KB -> 6 blocks/CU; out-proj 16 KB).
// 0-conflict XOR swizzle (4 octets/row): chunk p stores ko=(p&3)^(row&3);
// read slot = quad^(row&3)  [2-way bank aliasing = free, per m136].
template <int BM, int BN, bool OUT_BF16, bool SCALEQ>
__global__ __launch_bounds__(256) void gemm_bt_kernel(
    const bf16_t* __restrict__ A, const bf16_t* __restrict__ Bt,
    const float* __restrict__ bias, void* __restrict__ Cout,
    int M, int Nn, int K) {
  constexpr int BK = 32;
  constexpr int MT = BM / 32;
  constexpr int NT = BN / 32;
  constexpr int CA = BM / 64;              // A 16B-chunks per thread
  constexpr int CB = BN / 64;              // B 16B-chunks per thread
  __shared__ __align__(16) bf16_t As[2][BM * BK];
  __shared__ __align__(16) bf16_t Bs[2][BN * BK];
  int tid = threadIdx.x;
  int wave = tid >> 6, lane = tid & 63;
  int c = lane & 15, quad = lane >> 4;
  int bm = blockIdx.x * BM;
  int bn = blockIdx.y * BN;
  int wm = (wave & 1) * (BM / 2), wn = (wave >> 1) * (BN / 2);
  f32x4 acc[MT][NT] = {};

  // per-thread staging descriptors (chunk p = i*256 + tid)
  const bf16_t* agp[CA]; int alo[CA];
  const bf16_t* bgp[CB]; int blo[CB];
  #pragma unroll
  for (int i = 0; i < CA; ++i) {
    int p = i * 256 + tid;
    int row = p >> 2, ko = (p & 3) ^ (row & 3);
    agp[i] = A + (size_t)(bm + row) * K + ko * 8;
    alo[i] = (i * 256 + wave * 64) * 8;
  }
  #pragma unroll
  for (int i = 0; i < CB; ++i) {
    int p = i * 256 + tid;
    int row = p >> 2, ko = (p & 3) ^ (row & 3);
    bgp[i] = Bt + (size_t)(bn + row) * K + ko * 8;
    blo[i] = (i * 256 + wave * 64) * 8;
  }

  // prologue: tile 0 -> buffer 0
  #pragma unroll
  for (int i = 0; i < CA; ++i) async_copy16(agp[i], &As[0][alo[i]]);
  #pragma unroll
  for (int i = 0; i < CB; ++i) async_copy16(bgp[i], &Bs[0][blo[i]]);

  int nkb = K / BK;
  for (int ki = 0; ki < nkb; ++ki) {
    __syncthreads();   // drains tile-ki loads (issued one compute phase ago)
    if (ki + 1 < nkb) {
      int kb = (ki + 1) * BK;
      bf16_t* an = As[(ki + 1) & 1];
      bf16_t* bnx = Bs[(ki + 1) & 1];
      #pragma unroll
      for (int i = 0; i < CA; ++i) async_copy16(agp[i] + kb, an + alo[i]);
      #pragma unroll
      for (int i = 0; i < CB; ++i) async_copy16(bgp[i] + kb, bnx + blo[i]);
    }
    const bf16_t* as = As[ki & 1];
    const bf16_t* bs = Bs[ki & 1];
    bf16x8 af[MT], bf[NT];
    #pragma unroll
    for (int mt = 0; mt < MT; ++mt) {
      int row = wm + mt * 16 + c;
      int slot = quad ^ (row & 3);
      af[mt] = *(const bf16x8*)(as + (size_t)(row * 4 + slot) * 8);
    }
    #pragma unroll
    for (int nt = 0; nt < NT; ++nt) {
      int row = wn + nt * 16 + c;
      int slot = quad ^ (row & 3);
      bf[nt] = *(const bf16x8*)(bs + (size_t)(row * 4 + slot) * 8);
    }
    #pragma unroll
    for (int mt = 0; mt < MT; ++mt)
      #pragma unroll
      for (int nt = 0; nt < NT; ++nt)
        acc[mt][nt] = __builtin_amdgcn_mfma_f32_16x16x32_bf16(
            af[mt], bf[nt], acc[mt][nt], 0, 0, 0);
  }

  #pragma unroll
  for (int nt = 0; nt < NT; ++nt) {
    int col = bn + wn + nt * 16 + c;
    float bv = bias[col];
    float sc = (SCALEQ && col < HID) ? ATT_SCALE2 : 1.0f;
    #pragma unroll
    for (int mt = 0; mt < MT; ++mt) {
      #pragma unroll
      for (int r = 0; r < 4; ++r) {
        int row = bm + wm + mt * 16 + quad * 4 + r;   // C layout: row=(lane>>4)*4+reg
        float v = (acc[mt][nt][r] + bv) * sc;
        if (OUT_BF16)
          ((bf16_t*)Cout)[(size_t)row * Nn + col] = (bf16_t)v;
        else
          ((float*)Cout)[(size_t)row * Nn + col] = v;
      }
    }
  }
}

// ---------------- flash attention (unchanged) ------------------------------
__global__ __launch_bounds__(512, 4) void flash_attn_kernel(
    const bf16_t* __restrict__ Pj, const bf16_t* __restrict__ Vt,
    bf16_t* __restrict__ AO) {
  __shared__ __align__(16) bf16_t Ks[2][64 * 64];   // [j][d] swizzled
  __shared__ __align__(16) bf16_t Vs[2][64 * 64];   // [d][j] swizzled
  __shared__ __align__(16) bf16_t Ps[8][16 * 64];   // per-wave P[i][j] swizzled
  const int PJP = 3 * HID;
  int tid = threadIdx.x, wave = tid >> 6, lane = tid & 63;
  int c = lane & 15, quad = lane >> 4;
  int c7 = c & 7;
  int bid = blockIdx.x;
  int qb = (bid < 256) ? (15 - (bid >> 5)) : ((bid - 256) >> 5);
  int bh = bid & 31;
  int h = bh & 15, b = bh >> 4;
  int i0 = qb * 128;

  int i_row = i0 + wave * 16 + c;
  const bf16_t* qg = Pj + (size_t)(i_row * BATCH + b) * PJP + h * HDIM + quad * 8;
  bf16x8 qf0 = *(const bf16x8*)(qg);
  bf16x8 qf1 = *(const bf16x8*)(qg + 32);

  f32x4 o[4] = {};                   // O^T: rows d, col i=c
  float lrow = 0.f;

  int jr = tid >> 3, oc = tid & 7;
  int lds_off = jr * 64 + (oc ^ (jr & 7)) * 8;
  const bf16_t* kg0 = Pj + (size_t)b * PJP + HID + h * HDIM + oc * 8;
  const bf16_t* vg0 = Vt + (size_t)(bh * HDIM + jr) * N_SEQ + oc * 8;

  int njt = 2 * qb + 2;
  bf16x8 kreg = *(const bf16x8*)(kg0 + (size_t)jr * BATCH * PJP);
  bf16x8 vreg = *(const bf16x8*)(vg0);

  for (int jt = 0; jt < njt; ++jt) {
    bf16_t* ks = Ks[jt & 1];
    bf16_t* vs = Vs[jt & 1];
    *(bf16x8*)(ks + lds_off) = kreg;
    *(bf16x8*)(vs + lds_off) = vreg;
    __syncthreads();
    if (jt + 1 < njt) {
      int j0n = (jt + 1) * 64;
      kreg = *(const bf16x8*)(kg0 + (size_t)(j0n + jr) * BATCH * PJP);
      vreg = *(const bf16x8*)(vg0 + j0n);
    }

    f32x4 st[4];
    #pragma unroll
    for (int mt = 0; mt < 4; ++mt) {
      const bf16_t* kr = ks + (mt * 16 + c) * 64;
      bf16x8 ka0 = *(const bf16x8*)(kr + ((quad) ^ c7) * 8);
      bf16x8 ka1 = *(const bf16x8*)(kr + ((quad + 4) ^ c7) * 8);
      f32x4 s = {};
      s = __builtin_amdgcn_mfma_f32_16x16x32_bf16(ka0, qf0, s, 0, 0, 0);
      st[mt] = __builtin_amdgcn_mfma_f32_16x16x32_bf16(ka1, qf1, s, 0, 0, 0);
    }
    if (jt >= 2 * qb) {
      int j0 = jt * 64;
      int ig = i0 + wave * 16 + c;
      #pragma unroll
      for (int mt = 0; mt < 4; ++mt)
        #pragma unroll
        for (int r = 0; r < 4; ++r)
          if (j0 + mt * 16 + quad * 4 + r > ig) st[mt][r] = -1e30f;
    }

    #pragma unroll
    for (int mt = 0; mt < 4; ++mt)
      #pragma unroll
      for (int r = 0; r < 4; ++r) {
        st[mt][r] = EXP2F(st[mt][r]);
        lrow += st[mt][r];
      }

    bf16_t* pw = Ps[wave];
    #pragma unroll
    for (int mt = 0; mt < 4; ++mt) {
      bf16x4 pv;
      #pragma unroll
      for (int r = 0; r < 4; ++r) pv[r] = (bf16_t)st[mt][r];
      int joct = mt * 2 + (quad >> 1);
      *(bf16x4*)(pw + c * 64 + (joct ^ c7) * 8 + (quad & 1) * 4) = pv;
    }
    const bf16_t* pr = pw + c * 64;
    bf16x8 pa0 = *(const bf16x8*)(pr + ((quad) ^ c7) * 8);
    bf16x8 pa1 = *(const bf16x8*)(pr + ((quad + 4) ^ c7) * 8);

    #pragma unroll
    for (int nt = 0; nt < 4; ++nt) {
      const bf16_t* vr = vs + (nt * 16 + c) * 64;
      bf16x8 vb0 = *(const bf16x8*)(vr + ((quad) ^ c7) * 8);
      bf16x8 vb1 = *(const bf16x8*)(vr + ((quad + 4) ^ c7) * 8);
      o[nt] = __builtin_amdgcn_mfma_f32_16x16x32_bf16(vb0, pa0, o[nt], 0, 0, 0);
      o[nt] = __builtin_amdgcn_mfma_f32_16x16x32_bf16(vb1, pa1, o[nt], 0, 0, 0);
    }
  }

  float lfull = lrow;
  lfull += __shfl_xor(lfull, 16);
  lfull += __shfl_xor(lfull, 32);
  float linv = 1.0f / lfull;
  int orow = (i0 + wave * 16 + c) * BATCH + b;
  #pragma unroll
  for (int nt = 0; nt < 4; ++nt) {
    bf16x4 pv;
    #pragma unroll
    for (int r = 0; r < 4; ++r) pv[r] = (bf16_t)(o[nt][r] * linv);
    *(bf16x4*)(AO + (size_t)orow * HID + h * HDIM + nt * 16 + quad * 4) = pv;
  }
}

extern "C" void kernel_launch(void* const* d_in, const int* in_sizes, int n_in,
                              void* d_out, int out_size, void* d_ws, size_t ws_size,
                              hipStream_t stream) {
  const float* x      = (const float*)d_in[0];   // [2048][2][1024]
  const float* W_proj = (const float*)d_in[1];   // [1024][3072]
  const float* b_proj = (const float*)d_in[2];   // [3072]
  const float* W_out  = (const float*)d_in[3];   // [1024][1024]
  const float* b_out  = (const float*)d_in[4];   // [1024]

  bf16_t* Xb  = (bf16_t*)d_ws;                               // 4096*1024
  bf16_t* Wpt = Xb  + (size_t)NBROW * EMB;                   // 3072*1024
  bf16_t* Wot = Wpt + (size_t)3 * HID * EMB;                 // 1024*1024
  bf16_t* Pj  = Wot + (size_t)HID * EMB;                     // 4096*3072
  bf16_t* AO  = Pj  + (size_t)NBROW * 3 * HID;               // 4096*1024
  bf16_t* Vt  = AO  + (size_t)NBROW * HID;                   // 32*64*2048

  prep_kernel<<<8192, 256, 0, stream>>>(x, W_proj, W_out, Xb, Wpt, Wot);
  gemm_bt_kernel<128, 64, true, true>
      <<<dim3(NBROW / 128, 3 * HID / 64), 256, 0, stream>>>(
      Xb, Wpt, b_proj, (void*)Pj, NBROW, 3 * HID, EMB);
  vt_transpose_kernel<<<dim3(N_SEQ / 32, HDIM / 32, BATCH * NHEAD), 256, 0, stream>>>(
      Pj, Vt);
  flash_attn_kernel<<<512, 512, 0, stream>>>(Pj, Vt, AO);
  gemm_bt_kernel<64, 64, false, false>
      <<<dim3(NBROW / 64, EMB / 64), 256, 0, stream>>>(
      AO, Wot, b_out, d_out, NBROW, EMB, HID);
}

// Round 12
// 178.573 us; speedup vs baseline: 1.0138x; 1.0138x over previous
//
#include <hip/hip_runtime.h>
#include <cstdint>
#include <cstddef>

typedef __bf16 bf16_t;
typedef __bf16 bf16x8 __attribute__((ext_vector_type(8)));
typedef __bf16 bf16x4 __attribute__((ext_vector_type(4)));
typedef float f32x4 __attribute__((ext_vector_type(4)));

#define N_SEQ 2048
#define BATCH 2
#define EMB   1024
#define HID   1024
#define NHEAD 16
#define HDIM  64
#define NBROW (N_SEQ * BATCH)   /* 4096 GEMM rows (n*B+b) */
#define ATT_SCALE2 (0.03125f * 1.44269504f)  /* 1/sqrt(1024) * log2(e) */

#define EXP2F(x) __builtin_amdgcn_exp2f(x)   /* __exp2f collides with glibc macro */

static __device__ __forceinline__ void async_copy16(const bf16_t* g, bf16_t* l) {
  __builtin_amdgcn_global_load_lds((const __attribute__((address_space(1))) void*)g,
                                   (__attribute__((address_space(3))) void*)l,
                                   16, 0, 0);
}

// ---------------- fused prep: convert x + transpose both weights -----------
__global__ __launch_bounds__(256) void prep_kernel(
    const float* __restrict__ x, const float* __restrict__ Wp,
    const float* __restrict__ Wo, bf16_t* __restrict__ Xb,
    bf16_t* __restrict__ Wpt, bf16_t* __restrict__ Wot) {
  int bid = blockIdx.x;
  if (bid < 4096) {
    int i = (bid * 256 + threadIdx.x) * 4;
    float4 v = *(const float4*)(x + i);
    bf16x4 o;
    o[0] = (bf16_t)v.x; o[1] = (bf16_t)v.y; o[2] = (bf16_t)v.z; o[3] = (bf16_t)v.w;
    *(bf16x4*)(Xb + i) = o;
    return;
  }
  __shared__ float tile[32][33];
  const float* in; bf16_t* out; int R, C, bx;
  if (bid < 4096 + 3072) { bx = bid - 4096; in = Wp; out = Wpt; R = 1024; C = 3072; }
  else                   { bx = bid - 7168; in = Wo; out = Wot; R = 1024; C = 1024; }
  int gx = C / 32;
  int bc = (bx % gx) * 32, br = (bx / gx) * 32;
  int tx = threadIdx.x & 31, ty = threadIdx.x >> 5;   // 32 x 8
  #pragma unroll
  for (int i = 0; i < 32; i += 8)
    tile[ty + i][tx] = in[(size_t)(br + ty + i) * C + bc + tx];
  __syncthreads();
  #pragma unroll
  for (int i = 0; i < 32; i += 8)
    out[(size_t)(bc + ty + i) * R + br + tx] = (bf16_t)tile[tx][ty + i];
}

// ------- V transpose: Pj[n*B+b][2048 + h*64 + d] -> Vt[(b,h)][d][n] --------
__global__ void vt_transpose_kernel(const bf16_t* __restrict__ Pj,
                                    bf16_t* __restrict__ Vt) {
  __shared__ bf16_t tile[32][33];
  int tx = threadIdx.x & 31, ty = threadIdx.x >> 5;
  int n0 = blockIdx.x * 32, d0 = blockIdx.y * 32;
  int bh = blockIdx.z;
  int h = bh & 15, b = bh >> 4;
  const int PJP = 3 * HID;
  #pragma unroll
  for (int i = 0; i < 32; i += 8)
    tile[ty + i][tx] = Pj[(size_t)((n0 + ty + i) * BATCH + b) * PJP + 2 * HID + h * HDIM + d0 + tx];
  __syncthreads();
  #pragma unroll
  for (int i = 0; i < 32; i += 8)
    Vt[(size_t)(bh * HDIM + d0 + ty + i) * N_SEQ + n0 + tx] = tile[tx][ty + i];
}

// ---------------- pipelined GEMM: C = A * Bt^T + bias ----------------------
// BK=32 double-buffer, ONE barrier per K-iter (loads for tile ki+1 issued
// right after the barrier -> a full compute phase old at the next drain),
// small LDS (QKV 24 KB -> 6 blocks/CU; out-proj 16 KB -> 8 blocks/CU).
// CORRECTED 0-conflict swizzle (R5/R6-verified): bank group = 4*(row&1)+slot
// so slot must cycle with (row>>1): store chunk p holds octet
// ko=(p&3)^((p>>3)&3); read slot = quad^((row>>1)&3)  -> exact 2-way (free).
template <int BM, int BN, bool OUT_BF16, bool SCALEQ>
__global__ __launch_bounds__(256) void gemm_bt_kernel(
    const bf16_t* __restrict__ A, const bf16_t* __restrict__ Bt,
    const float* __restrict__ bias, void* __restrict__ Cout,
    int M, int Nn, int K) {
  constexpr int BK = 32;
  constexpr int MT = BM / 32;
  constexpr int NT = BN / 32;
  constexpr int CA = BM / 64;              // A 16B-chunks per thread
  constexpr int CB = BN / 64;              // B 16B-chunks per thread
  __shared__ __align__(16) bf16_t As[2][BM * BK];
  __shared__ __align__(16) bf16_t Bs[2][BN * BK];
  int tid = threadIdx.x;
  int wave = tid >> 6, lane = tid & 63;
  int c = lane & 15, quad = lane >> 4;
  int bm = blockIdx.x * BM;
  int bn = blockIdx.y * BN;
  int wm = (wave & 1) * (BM / 2), wn = (wave >> 1) * (BN / 2);
  f32x4 acc[MT][NT] = {};

  // per-thread staging descriptors (chunk p = i*256 + tid)
  const bf16_t* agp[CA]; int alo[CA];
  const bf16_t* bgp[CB]; int blo[CB];
  #pragma unroll
  for (int i = 0; i < CA; ++i) {
    int p = i * 256 + tid;
    int row = p >> 2, ko = (p & 3) ^ ((p >> 3) & 3);   // (row>>1)&3 = (p>>3)&3
    agp[i] = A + (size_t)(bm + row) * K + ko * 8;
    alo[i] = (i * 256 + wave * 64) * 8;
  }
  #pragma unroll
  for (int i = 0; i < CB; ++i) {
    int p = i * 256 + tid;
    int row = p >> 2, ko = (p & 3) ^ ((p >> 3) & 3);
    bgp[i] = Bt + (size_t)(bn + row) * K + ko * 8;
    blo[i] = (i * 256 + wave * 64) * 8;
  }

  // prologue: tile 0 -> buffer 0
  #pragma unroll
  for (int i = 0; i < CA; ++i) async_copy16(agp[i], &As[0][alo[i]]);
  #pragma unroll
  for (int i = 0; i < CB; ++i) async_copy16(bgp[i], &Bs[0][blo[i]]);

  int nkb = K / BK;
  for (int ki = 0; ki < nkb; ++ki) {
    __syncthreads();   // drains tile-ki loads (issued one compute phase ago)
    if (ki + 1 < nkb) {
      int kb = (ki + 1) * BK;
      bf16_t* an = As[(ki + 1) & 1];
      bf16_t* bnx = Bs[(ki + 1) & 1];
      #pragma unroll
      for (int i = 0; i < CA; ++i) async_copy16(agp[i] + kb, an + alo[i]);
      #pragma unroll
      for (int i = 0; i < CB; ++i) async_copy16(bgp[i] + kb, bnx + blo[i]);
    }
    const bf16_t* as = As[ki & 1];
    const bf16_t* bs = Bs[ki & 1];
    bf16x8 af[MT], bf[NT];
    #pragma unroll
    for (int mt = 0; mt < MT; ++mt) {
      int row = wm + mt * 16 + c;
      int slot = quad ^ ((row >> 1) & 3);
      af[mt] = *(const bf16x8*)(as + (size_t)(row * 4 + slot) * 8);
    }
    #pragma unroll
    for (int nt = 0; nt < NT; ++nt) {
      int row = wn + nt * 16 + c;
      int slot = quad ^ ((row >> 1) & 3);
      bf[nt] = *(const bf16x8*)(bs + (size_t)(row * 4 + slot) * 8);
    }
    #pragma unroll
    for (int mt = 0; mt < MT; ++mt)
      #pragma unroll
      for (int nt = 0; nt < NT; ++nt)
        acc[mt][nt] = __builtin_amdgcn_mfma_f32_16x16x32_bf16(
            af[mt], bf[nt], acc[mt][nt], 0, 0, 0);
  }

  #pragma unroll
  for (int nt = 0; nt < NT; ++nt) {
    int col = bn + wn + nt * 16 + c;
    float bv = bias[col];
    float sc = (SCALEQ && col < HID) ? ATT_SCALE2 : 1.0f;
    #pragma unroll
    for (int mt = 0; mt < MT; ++mt) {
      #pragma unroll
      for (int r = 0; r < 4; ++r) {
        int row = bm + wm + mt * 16 + quad * 4 + r;   // C layout: row=(lane>>4)*4+reg
        float v = (acc[mt][nt][r] + bv) * sc;
        if (OUT_BF16)
          ((bf16_t*)Cout)[(size_t)row * Nn + col] = (bf16_t)v;
        else
          ((float*)Cout)[(size_t)row * Nn + col] = v;
      }
    }
  }
}

// ---------------- flash attention (unchanged) ------------------------------
__global__ __launch_bounds__(512, 4) void flash_attn_kernel(
    const bf16_t* __restrict__ Pj, const bf16_t* __restrict__ Vt,
    bf16_t* __restrict__ AO) {
  __shared__ __align__(16) bf16_t Ks[2][64 * 64];   // [j][d] swizzled
  __shared__ __align__(16) bf16_t Vs[2][64 * 64];   // [d][j] swizzled
  __shared__ __align__(16) bf16_t Ps[8][16 * 64];   // per-wave P[i][j] swizzled
  const int PJP = 3 * HID;
  int tid = threadIdx.x, wave = tid >> 6, lane = tid & 63;
  int c = lane & 15, quad = lane >> 4;
  int c7 = c & 7;
  int bid = blockIdx.x;
  int qb = (bid < 256) ? (15 - (bid >> 5)) : ((bid - 256) >> 5);
  int bh = bid & 31;
  int h = bh & 15, b = bh >> 4;
  int i0 = qb * 128;

  int i_row = i0 + wave * 16 + c;
  const bf16_t* qg = Pj + (size_t)(i_row * BATCH + b) * PJP + h * HDIM + quad * 8;
  bf16x8 qf0 = *(const bf16x8*)(qg);
  bf16x8 qf1 = *(const bf16x8*)(qg + 32);

  f32x4 o[4] = {};                   // O^T: rows d, col i=c
  float lrow = 0.f;

  int jr = tid >> 3, oc = tid & 7;
  int lds_off = jr * 64 + (oc ^ (jr & 7)) * 8;
  const bf16_t* kg0 = Pj + (size_t)b * PJP + HID + h * HDIM + oc * 8;
  const bf16_t* vg0 = Vt + (size_t)(bh * HDIM + jr) * N_SEQ + oc * 8;

  int njt = 2 * qb + 2;
  bf16x8 kreg = *(const bf16x8*)(kg0 + (size_t)jr * BATCH * PJP);
  bf16x8 vreg = *(const bf16x8*)(vg0);

  for (int jt = 0; jt < njt; ++jt) {
    bf16_t* ks = Ks[jt & 1];
    bf16_t* vs = Vs[jt & 1];
    *(bf16x8*)(ks + lds_off) = kreg;
    *(bf16x8*)(vs + lds_off) = vreg;
    __syncthreads();
    if (jt + 1 < njt) {
      int j0n = (jt + 1) * 64;
      kreg = *(const bf16x8*)(kg0 + (size_t)(j0n + jr) * BATCH * PJP);
      vreg = *(const bf16x8*)(vg0 + j0n);
    }

    f32x4 st[4];
    #pragma unroll
    for (int mt = 0; mt < 4; ++mt) {
      const bf16_t* kr = ks + (mt * 16 + c) * 64;
      bf16x8 ka0 = *(const bf16x8*)(kr + ((quad) ^ c7) * 8);
      bf16x8 ka1 = *(const bf16x8*)(kr + ((quad + 4) ^ c7) * 8);
      f32x4 s = {};
      s = __builtin_amdgcn_mfma_f32_16x16x32_bf16(ka0, qf0, s, 0, 0, 0);
      st[mt] = __builtin_amdgcn_mfma_f32_16x16x32_bf16(ka1, qf1, s, 0, 0, 0);
    }
    if (jt >= 2 * qb) {
      int j0 = jt * 64;
      int ig = i0 + wave * 16 + c;
      #pragma unroll
      for (int mt = 0; mt < 4; ++mt)
        #pragma unroll
        for (int r = 0; r < 4; ++r)
          if (j0 + mt * 16 + quad * 4 + r > ig) st[mt][r] = -1e30f;
    }

    #pragma unroll
    for (int mt = 0; mt < 4; ++mt)
      #pragma unroll
      for (int r = 0; r < 4; ++r) {
        st[mt][r] = EXP2F(st[mt][r]);
        lrow += st[mt][r];
      }

    bf16_t* pw = Ps[wave];
    #pragma unroll
    for (int mt = 0; mt < 4; ++mt) {
      bf16x4 pv;
      #pragma unroll
      for (int r = 0; r < 4; ++r) pv[r] = (bf16_t)st[mt][r];
      int joct = mt * 2 + (quad >> 1);
      *(bf16x4*)(pw + c * 64 + (joct ^ c7) * 8 + (quad & 1) * 4) = pv;
    }
    const bf16_t* pr = pw + c * 64;
    bf16x8 pa0 = *(const bf16x8*)(pr + ((quad) ^ c7) * 8);
    bf16x8 pa1 = *(const bf16x8*)(pr + ((quad + 4) ^ c7) * 8);

    #pragma unroll
    for (int nt = 0; nt < 4; ++nt) {
      const bf16_t* vr = vs + (nt * 16 + c) * 64;
      bf16x8 vb0 = *(const bf16x8*)(vr + ((quad) ^ c7) * 8);
      bf16x8 vb1 = *(const bf16x8*)(vr + ((quad + 4) ^ c7) * 8);
      o[nt] = __builtin_amdgcn_mfma_f32_16x16x32_bf16(vb0, pa0, o[nt], 0, 0, 0);
      o[nt] = __builtin_amdgcn_mfma_f32_16x16x32_bf16(vb1, pa1, o[nt], 0, 0, 0);
    }
  }

  float lfull = lrow;
  lfull += __shfl_xor(lfull, 16);
  lfull += __shfl_xor(lfull, 32);
  float linv = 1.0f / lfull;
  int orow = (i0 + wave * 16 + c) * BATCH + b;
  #pragma unroll
  for (int nt = 0; nt < 4; ++nt) {
    bf16x4 pv;
    #pragma unroll
    for (int r = 0; r < 4; ++r) pv[r] = (bf16_t)(o[nt][r] * linv);
    *(bf16x4*)(AO + (size_t)orow * HID + h * HDIM + nt * 16 + quad * 4) = pv;
  }
}

extern "C" void kernel_launch(void* const* d_in, const int* in_sizes, int n_in,
                              void* d_out, int out_size, void* d_ws, size_t ws_size,
                              hipStream_t stream) {
  const float* x      = (const float*)d_in[0];   // [2048][2][1024]
  const float* W_proj = (const float*)d_in[1];   // [1024][3072]
  const float* b_proj = (const float*)d_in[2];   // [3072]
  const float* W_out  = (const float*)d_in[3];   // [1024][1024]
  const float* b_out  = (const float*)d_in[4];   // [1024]

  bf16_t* Xb  = (bf16_t*)d_ws;                               // 4096*1024
  bf16_t* Wpt = Xb  + (size_t)NBROW * EMB;                   // 3072*1024
  bf16_t* Wot = Wpt + (size_t)3 * HID * EMB;                 // 1024*1024
  bf16_t* Pj  = Wot + (size_t)HID * EMB;                     // 4096*3072
  bf16_t* AO  = Pj  + (size_t)NBROW * 3 * HID;               // 4096*1024
  bf16_t* Vt  = AO  + (size_t)NBROW * HID;                   // 32*64*2048

  prep_kernel<<<8192, 256, 0, stream>>>(x, W_proj, W_out, Xb, Wpt, Wot);
  gemm_bt_kernel<128, 64, true, true>
      <<<dim3(NBROW / 128, 3 * HID / 64), 256, 0, stream>>>(
      Xb, Wpt, b_proj, (void*)Pj, NBROW, 3 * HID, EMB);
  vt_transpose_kernel<<<dim3(N_SEQ / 32, HDIM / 32, BATCH * NHEAD), 256, 0, stream>>>(
      Pj, Vt);
  flash_attn_kernel<<<512, 512, 0, stream>>>(Pj, Vt, AO);
  gemm_bt_kernel<64, 64, false, false>
      <<<dim3(NBROW / 64, EMB / 64), 256, 0, stream>>>(
      AO, Wot, b_out, d_out, NBROW, EMB, HID);
}

// Round 13
// 164.277 us; speedup vs baseline: 1.1020x; 1.0870x over previous
//
#include <hip/hip_runtime.h>
#include <cstdint>
#include <cstddef>

typedef __bf16 bf16_t;
typedef __bf16 bf16x8 __attribute__((ext_vector_type(8)));
typedef __bf16 bf16x4 __attribute__((ext_vector_type(4)));
typedef float f32x4 __attribute__((ext_vector_type(4)));

#define N_SEQ 2048
#define BATCH 2
#define EMB   1024
#define HID   1024
#define NHEAD 16
#define HDIM  64
#define NBROW (N_SEQ * BATCH)   /* 4096 GEMM rows (n*B+b) */
#define ATT_SCALE2 (0.03125f * 1.44269504f)  /* 1/sqrt(1024) * log2(e) */

#define EXP2F(x) __builtin_amdgcn_exp2f(x)   /* __exp2f collides with glibc macro */

static __device__ __forceinline__ void async_copy16(const bf16_t* g, bf16_t* l) {
  __builtin_amdgcn_global_load_lds((const __attribute__((address_space(1))) void*)g,
                                   (__attribute__((address_space(3))) void*)l,
                                   16, 0, 0);
}

// ---------------- fused prep: convert x + transpose both weights -----------
__global__ __launch_bounds__(256) void prep_kernel(
    const float* __restrict__ x, const float* __restrict__ Wp,
    const float* __restrict__ Wo, bf16_t* __restrict__ Xb,
    bf16_t* __restrict__ Wpt, bf16_t* __restrict__ Wot) {
  int bid = blockIdx.x;
  if (bid < 4096) {
    int i = (bid * 256 + threadIdx.x) * 4;
    float4 v = *(const float4*)(x + i);
    bf16x4 o;
    o[0] = (bf16_t)v.x; o[1] = (bf16_t)v.y; o[2] = (bf16_t)v.z; o[3] = (bf16_t)v.w;
    *(bf16x4*)(Xb + i) = o;
    return;
  }
  __shared__ float tile[32][33];
  const float* in; bf16_t* out; int R, C, bx;
  if (bid < 4096 + 3072) { bx = bid - 4096; in = Wp; out = Wpt; R = 1024; C = 3072; }
  else                   { bx = bid - 7168; in = Wo; out = Wot; R = 1024; C = 1024; }
  int gx = C / 32;
  int bc = (bx % gx) * 32, br = (bx / gx) * 32;
  int tx = threadIdx.x & 31, ty = threadIdx.x >> 5;   // 32 x 8
  #pragma unroll
  for (int i = 0; i < 32; i += 8)
    tile[ty + i][tx] = in[(size_t)(br + ty + i) * C + bc + tx];
  __syncthreads();
  #pragma unroll
  for (int i = 0; i < 32; i += 8)
    out[(size_t)(bc + ty + i) * R + br + tx] = (bf16_t)tile[tx][ty + i];
}

// ---------------- pipelined GEMM: C = A * Bt^T + bias ----------------------
// BK=64 double-buffer (R10's best config: 16 barrier drains, loads a full
// compute phase old at each drain). Verified-0-conflict swizzle: chunk p
// stores octet ko=(p&7)^(row&7); read slot = (kk*4+quad)^(row&7).
// WRITE_VT (QKV only): blocks covering cols >= 2048 (the V third) also emit
// V^T into Vt[(b*16+h)][d][n] via an LDS round-trip (coalesced 16B stores),
// replacing the standalone vt_transpose kernel + its launch gap.
template <int BM, int BN, bool OUT_BF16, bool SCALEQ, bool WRITE_VT>
__global__ __launch_bounds__(256) void gemm_bt_kernel(
    const bf16_t* __restrict__ A, const bf16_t* __restrict__ Bt,
    const float* __restrict__ bias, void* __restrict__ Cout,
    bf16_t* __restrict__ Vt, int M, int Nn, int K) {
  constexpr int BK = 64;
  constexpr int MT = BM / 32;
  constexpr int NT = BN / 32;
  constexpr int CA = BM / 32;              // A 16B-chunks per thread
  constexpr int CB = BN / 32;              // B 16B-chunks per thread
  __shared__ __align__(16) bf16_t As[2][BM * BK];
  __shared__ __align__(16) bf16_t Bs[2][BN * BK];
  int tid = threadIdx.x;
  int wave = tid >> 6, lane = tid & 63;
  int c = lane & 15, quad = lane >> 4;
  int bm = blockIdx.x * BM;
  int bn = blockIdx.y * BN;
  int wm = (wave & 1) * (BM / 2), wn = (wave >> 1) * (BN / 2);
  f32x4 acc[MT][NT] = {};

  // per-thread staging descriptors (chunk p = i*256 + tid)
  const bf16_t* agp[CA]; int alo[CA];
  const bf16_t* bgp[CB]; int blo[CB];
  #pragma unroll
  for (int i = 0; i < CA; ++i) {
    int p = i * 256 + tid;
    int row = p >> 3, ko = (p & 7) ^ (row & 7);
    agp[i] = A + (size_t)(bm + row) * K + ko * 8;
    alo[i] = (i * 256 + wave * 64) * 8;
  }
  #pragma unroll
  for (int i = 0; i < CB; ++i) {
    int p = i * 256 + tid;
    int row = p >> 3, ko = (p & 7) ^ (row & 7);
    bgp[i] = Bt + (size_t)(bn + row) * K + ko * 8;
    blo[i] = (i * 256 + wave * 64) * 8;
  }

  // prologue: tile 0 -> buffer 0
  #pragma unroll
  for (int i = 0; i < CA; ++i) async_copy16(agp[i], &As[0][alo[i]]);
  #pragma unroll
  for (int i = 0; i < CB; ++i) async_copy16(bgp[i], &Bs[0][blo[i]]);

  int nkb = K / BK;
  for (int ki = 0; ki < nkb; ++ki) {
    __syncthreads();   // drains tile-ki loads (issued one compute phase ago)
    if (ki + 1 < nkb) {
      int kb = (ki + 1) * BK;
      bf16_t* an = As[(ki + 1) & 1];
      bf16_t* bnx = Bs[(ki + 1) & 1];
      #pragma unroll
      for (int i = 0; i < CA; ++i) async_copy16(agp[i] + kb, an + alo[i]);
      #pragma unroll
      for (int i = 0; i < CB; ++i) async_copy16(bgp[i] + kb, bnx + blo[i]);
    }
    const bf16_t* as = As[ki & 1];
    const bf16_t* bs = Bs[ki & 1];
    #pragma unroll
    for (int kk = 0; kk < 2; ++kk) {
      bf16x8 af[MT], bf[NT];
      #pragma unroll
      for (int mt = 0; mt < MT; ++mt) {
        int row = wm + mt * 16 + c;
        int slot = (kk * 4 + quad) ^ (row & 7);
        af[mt] = *(const bf16x8*)(as + (size_t)(row * 8 + slot) * 8);
      }
      #pragma unroll
      for (int nt = 0; nt < NT; ++nt) {
        int row = wn + nt * 16 + c;
        int slot = (kk * 4 + quad) ^ (row & 7);
        bf[nt] = *(const bf16x8*)(bs + (size_t)(row * 8 + slot) * 8);
      }
      #pragma unroll
      for (int mt = 0; mt < MT; ++mt)
        #pragma unroll
        for (int nt = 0; nt < NT; ++nt)
          acc[mt][nt] = __builtin_amdgcn_mfma_f32_16x16x32_bf16(
              af[mt], bf[nt], acc[mt][nt], 0, 0, 0);
    }
  }

  bool do_vt = WRITE_VT && (bn >= 2 * HID);
  bf16_t* tb = (bf16_t*)As[0];   // reuse As for V^T staging: 2*64*72*2B < 32KB
  if (do_vt) __syncthreads();    // last tile's ds_reads done before As reuse

  #pragma unroll
  for (int nt = 0; nt < NT; ++nt) {
    int col = bn + wn + nt * 16 + c;
    float bv = bias[col];
    float sc = (SCALEQ && col < HID) ? ATT_SCALE2 : 1.0f;
    #pragma unroll
    for (int mt = 0; mt < MT; ++mt) {
      #pragma unroll
      for (int r = 0; r < 4; ++r) {
        int loc = wm + mt * 16 + quad * 4 + r;        // row within tile
        int row = bm + loc;                           // C layout: row=(lane>>4)*4+reg
        float v = (acc[mt][nt][r] + bv) * sc;
        if (OUT_BF16)
          ((bf16_t*)Cout)[(size_t)row * Nn + col] = (bf16_t)v;
        else
          ((float*)Cout)[(size_t)row * Nn + col] = v;
        if (do_vt) {
          int d = wn + nt * 16 + c;                   // col within head (BN=64)
          tb[(loc & 1) * 4608 + d * 72 + (loc >> 1)] = (bf16_t)v;
        }
      }
    }
  }

  if (do_vt) {
    __syncthreads();
    int h = (bn - 2 * HID) >> 6;
    int n2 = (tid & 7) * 8;
    #pragma unroll
    for (int i = 0; i < 2; ++i) {        // batch b
      #pragma unroll
      for (int k = 0; k < 2; ++k) {
        int d = (tid >> 3) + k * 32;
        bf16x8 vv = *(const bf16x8*)(tb + i * 4608 + d * 72 + n2);
        *(bf16x8*)(Vt + (size_t)((i * 16 + h) * HDIM + d) * N_SEQ + bm / 2 + n2) = vv;
      }
    }
  }
}

// ---------------- flash attention (unchanged) ------------------------------
__global__ __launch_bounds__(512, 4) void flash_attn_kernel(
    const bf16_t* __restrict__ Pj, const bf16_t* __restrict__ Vt,
    bf16_t* __restrict__ AO) {
  __shared__ __align__(16) bf16_t Ks[2][64 * 64];   // [j][d] swizzled
  __shared__ __align__(16) bf16_t Vs[2][64 * 64];   // [d][j] swizzled
  __shared__ __align__(16) bf16_t Ps[8][16 * 64];   // per-wave P[i][j] swizzled
  const int PJP = 3 * HID;
  int tid = threadIdx.x, wave = tid >> 6, lane = tid & 63;
  int c = lane & 15, quad = lane >> 4;
  int c7 = c & 7;
  int bid = blockIdx.x;
  int qb = (bid < 256) ? (15 - (bid >> 5)) : ((bid - 256) >> 5);
  int bh = bid & 31;
  int h = bh & 15, b = bh >> 4;
  int i0 = qb * 128;

  int i_row = i0 + wave * 16 + c;
  const bf16_t* qg = Pj + (size_t)(i_row * BATCH + b) * PJP + h * HDIM + quad * 8;
  bf16x8 qf0 = *(const bf16x8*)(qg);
  bf16x8 qf1 = *(const bf16x8*)(qg + 32);

  f32x4 o[4] = {};                   // O^T: rows d, col i=c
  float lrow = 0.f;

  int jr = tid >> 3, oc = tid & 7;
  int lds_off = jr * 64 + (oc ^ (jr & 7)) * 8;
  const bf16_t* kg0 = Pj + (size_t)b * PJP + HID + h * HDIM + oc * 8;
  const bf16_t* vg0 = Vt + (size_t)(bh * HDIM + jr) * N_SEQ + oc * 8;

  int njt = 2 * qb + 2;
  bf16x8 kreg = *(const bf16x8*)(kg0 + (size_t)jr * BATCH * PJP);
  bf16x8 vreg = *(const bf16x8*)(vg0);

  for (int jt = 0; jt < njt; ++jt) {
    bf16_t* ks = Ks[jt & 1];
    bf16_t* vs = Vs[jt & 1];
    *(bf16x8*)(ks + lds_off) = kreg;
    *(bf16x8*)(vs + lds_off) = vreg;
    __syncthreads();
    if (jt + 1 < njt) {
      int j0n = (jt + 1) * 64;
      kreg = *(const bf16x8*)(kg0 + (size_t)(j0n + jr) * BATCH * PJP);
      vreg = *(const bf16x8*)(vg0 + j0n);
    }

    f32x4 st[4];
    #pragma unroll
    for (int mt = 0; mt < 4; ++mt) {
      const bf16_t* kr = ks + (mt * 16 + c) * 64;
      bf16x8 ka0 = *(const bf16x8*)(kr + ((quad) ^ c7) * 8);
      bf16x8 ka1 = *(const bf16x8*)(kr + ((quad + 4) ^ c7) * 8);
      f32x4 s = {};
      s = __builtin_amdgcn_mfma_f32_16x16x32_bf16(ka0, qf0, s, 0, 0, 0);
      st[mt] = __builtin_amdgcn_mfma_f32_16x16x32_bf16(ka1, qf1, s, 0, 0, 0);
    }
    if (jt >= 2 * qb) {
      int j0 = jt * 64;
      int ig = i0 + wave * 16 + c;
      #pragma unroll
      for (int mt = 0; mt < 4; ++mt)
        #pragma unroll
        for (int r = 0; r < 4; ++r)
          if (j0 + mt * 16 + quad * 4 + r > ig) st[mt][r] = -1e30f;
    }

    #pragma unroll
    for (int mt = 0; mt < 4; ++mt)
      #pragma unroll
      for (int r = 0; r < 4; ++r) {
        st[mt][r] = EXP2F(st[mt][r]);
        lrow += st[mt][r];
      }

    bf16_t* pw = Ps[wave];
    #pragma unroll
    for (int mt = 0; mt < 4; ++mt) {
      bf16x4 pv;
      #pragma unroll
      for (int r = 0; r < 4; ++r) pv[r] = (bf16_t)st[mt][r];
      int joct = mt * 2 + (quad >> 1);
      *(bf16x4*)(pw + c * 64 + (joct ^ c7) * 8 + (quad & 1) * 4) = pv;
    }
    const bf16_t* pr = pw + c * 64;
    bf16x8 pa0 = *(const bf16x8*)(pr + ((quad) ^ c7) * 8);
    bf16x8 pa1 = *(const bf16x8*)(pr + ((quad + 4) ^ c7) * 8);

    #pragma unroll
    for (int nt = 0; nt < 4; ++nt) {
      const bf16_t* vr = vs + (nt * 16 + c) * 64;
      bf16x8 vb0 = *(const bf16x8*)(vr + ((quad) ^ c7) * 8);
      bf16x8 vb1 = *(const bf16x8*)(vr + ((quad + 4) ^ c7) * 8);
      o[nt] = __builtin_amdgcn_mfma_f32_16x16x32_bf16(vb0, pa0, o[nt], 0, 0, 0);
      o[nt] = __builtin_amdgcn_mfma_f32_16x16x32_bf16(vb1, pa1, o[nt], 0, 0, 0);
    }
  }

  float lfull = lrow;
  lfull += __shfl_xor(lfull, 16);
  lfull += __shfl_xor(lfull, 32);
  float linv = 1.0f / lfull;
  int orow = (i0 + wave * 16 + c) * BATCH + b;
  #pragma unroll
  for (int nt = 0; nt < 4; ++nt) {
    bf16x4 pv;
    #pragma unroll
    for (int r = 0; r < 4; ++r) pv[r] = (bf16_t)(o[nt][r] * linv);
    *(bf16x4*)(AO + (size_t)orow * HID + h * HDIM + nt * 16 + quad * 4) = pv;
  }
}

extern "C" void kernel_launch(void* const* d_in, const int* in_sizes, int n_in,
                              void* d_out, int out_size, void* d_ws, size_t ws_size,
                              hipStream_t stream) {
  const float* x      = (const float*)d_in[0];   // [2048][2][1024]
  const float* W_proj = (const float*)d_in[1];   // [1024][3072]
  const float* b_proj = (const float*)d_in[2];   // [3072]
  const float* W_out  = (const float*)d_in[3];   // [1024][1024]
  const float* b_out  = (const float*)d_in[4];   // [1024]

  bf16_t* Xb  = (bf16_t*)d_ws;                               // 4096*1024
  bf16_t* Wpt = Xb  + (size_t)NBROW * EMB;                   // 3072*1024
  bf16_t* Wot = Wpt + (size_t)3 * HID * EMB;                 // 1024*1024
  bf16_t* Pj  = Wot + (size_t)HID * EMB;                     // 4096*3072
  bf16_t* AO  = Pj  + (size_t)NBROW * 3 * HID;               // 4096*1024
  bf16_t* Vt  = AO  + (size_t)NBROW * HID;                   // 32*64*2048

  prep_kernel<<<8192, 256, 0, stream>>>(x, W_proj, W_out, Xb, Wpt, Wot);
  gemm_bt_kernel<128, 64, true, true, true>
      <<<dim3(NBROW / 128, 3 * HID / 64), 256, 0, stream>>>(
      Xb, Wpt, b_proj, (void*)Pj, Vt, NBROW, 3 * HID, EMB);
  flash_attn_kernel<<<512, 512, 0, stream>>>(Pj, Vt, AO);
  gemm_bt_kernel<64, 64, false, false, false>
      <<<dim3(NBROW / 64, EMB / 64), 256, 0, stream>>>(
      AO, Wot, b_out, d_out, nullptr, NBROW, EMB, HID);
}

// Round 14
// 163.751 us; speedup vs baseline: 1.1056x; 1.0032x over previous
//
#include <hip/hip_runtime.h>
#include <cstdint>
#include <cstddef>

typedef __bf16 bf16_t;
typedef __bf16 bf16x8 __attribute__((ext_vector_type(8)));
typedef __bf16 bf16x4 __attribute__((ext_vector_type(4)));
typedef float f32x4 __attribute__((ext_vector_type(4)));

#define N_SEQ 2048
#define BATCH 2
#define EMB   1024
#define HID   1024
#define NHEAD 16
#define HDIM  64
#define NBROW (N_SEQ * BATCH)   /* 4096 GEMM rows (n*B+b) */
#define ATT_SCALE2 (0.03125f * 1.44269504f)  /* 1/sqrt(1024) * log2(e) */

#define EXP2F(x) __builtin_amdgcn_exp2f(x)   /* __exp2f collides with glibc macro */

static __device__ __forceinline__ void async_copy16(const bf16_t* g, bf16_t* l) {
  __builtin_amdgcn_global_load_lds((const __attribute__((address_space(1))) void*)g,
                                   (__attribute__((address_space(3))) void*)l,
                                   16, 0, 0);
}

// ---------------- fused prep: convert x + transpose both weights -----------
__global__ __launch_bounds__(256) void prep_kernel(
    const float* __restrict__ x, const float* __restrict__ Wp,
    const float* __restrict__ Wo, bf16_t* __restrict__ Xb,
    bf16_t* __restrict__ Wpt, bf16_t* __restrict__ Wot) {
  int bid = blockIdx.x;
  if (bid < 4096) {
    int i = (bid * 256 + threadIdx.x) * 4;
    float4 v = *(const float4*)(x + i);
    bf16x4 o;
    o[0] = (bf16_t)v.x; o[1] = (bf16_t)v.y; o[2] = (bf16_t)v.z; o[3] = (bf16_t)v.w;
    *(bf16x4*)(Xb + i) = o;
    return;
  }
  __shared__ float tile[32][33];
  const float* in; bf16_t* out; int R, C, bx;
  if (bid < 4096 + 3072) { bx = bid - 4096; in = Wp; out = Wpt; R = 1024; C = 3072; }
  else                   { bx = bid - 7168; in = Wo; out = Wot; R = 1024; C = 1024; }
  int gx = C / 32;
  int bc = (bx % gx) * 32, br = (bx / gx) * 32;
  int tx = threadIdx.x & 31, ty = threadIdx.x >> 5;   // 32 x 8
  #pragma unroll
  for (int i = 0; i < 32; i += 8)
    tile[ty + i][tx] = in[(size_t)(br + ty + i) * C + bc + tx];
  __syncthreads();
  #pragma unroll
  for (int i = 0; i < 32; i += 8)
    out[(size_t)(bc + ty + i) * R + br + tx] = (bf16_t)tile[tx][ty + i];
}

// ---------------- pipelined GEMM: C = A * Bt^T + bias ----------------------
// BK=64 double-buffer: ONE barrier per K-iter; next tile's loads issued
// right after the barrier (a full compute phase old at the next drain).
// Verified-0-conflict swizzle: chunk p stores octet ko=(p&7)^(row&7);
// read slot = (kk*4+quad)^(row&7).
// WRITE_VT (QKV only): blocks covering cols >= 2048 (the V third) also emit
// V^T into Vt[(b*16+h)][d][n] via an LDS round-trip (coalesced 16B stores).
template <int BM, int BN, bool OUT_BF16, bool SCALEQ, bool WRITE_VT>
__global__ __launch_bounds__(256) void gemm_bt_kernel(
    const bf16_t* __restrict__ A, const bf16_t* __restrict__ Bt,
    const float* __restrict__ bias, void* __restrict__ Cout,
    bf16_t* __restrict__ Vt, int M, int Nn, int K) {
  constexpr int BK = 64;
  constexpr int MT = BM / 32;
  constexpr int NT = BN / 32;
  constexpr int CA = BM / 32;              // A 16B-chunks per thread
  constexpr int CB = BN / 32;              // B 16B-chunks per thread
  __shared__ __align__(16) bf16_t As[2][BM * BK];
  __shared__ __align__(16) bf16_t Bs[2][BN * BK];
  int tid = threadIdx.x;
  int wave = tid >> 6, lane = tid & 63;
  int c = lane & 15, quad = lane >> 4;
  int bm = blockIdx.x * BM;
  int bn = blockIdx.y * BN;
  int wm = (wave & 1) * (BM / 2), wn = (wave >> 1) * (BN / 2);
  f32x4 acc[MT][NT] = {};

  // per-thread staging descriptors (chunk p = i*256 + tid)
  const bf16_t* agp[CA]; int alo[CA];
  const bf16_t* bgp[CB]; int blo[CB];
  #pragma unroll
  for (int i = 0; i < CA; ++i) {
    int p = i * 256 + tid;
    int row = p >> 3, ko = (p & 7) ^ (row & 7);
    agp[i] = A + (size_t)(bm + row) * K + ko * 8;
    alo[i] = (i * 256 + wave * 64) * 8;
  }
  #pragma unroll
  for (int i = 0; i < CB; ++i) {
    int p = i * 256 + tid;
    int row = p >> 3, ko = (p & 7) ^ (row & 7);
    bgp[i] = Bt + (size_t)(bn + row) * K + ko * 8;
    blo[i] = (i * 256 + wave * 64) * 8;
  }

  // prologue: tile 0 -> buffer 0
  #pragma unroll
  for (int i = 0; i < CA; ++i) async_copy16(agp[i], &As[0][alo[i]]);
  #pragma unroll
  for (int i = 0; i < CB; ++i) async_copy16(bgp[i], &Bs[0][blo[i]]);

  int nkb = K / BK;
  for (int ki = 0; ki < nkb; ++ki) {
    __syncthreads();   // drains tile-ki loads (issued one compute phase ago)
    if (ki + 1 < nkb) {
      int kb = (ki + 1) * BK;
      bf16_t* an = As[(ki + 1) & 1];
      bf16_t* bnx = Bs[(ki + 1) & 1];
      #pragma unroll
      for (int i = 0; i < CA; ++i) async_copy16(agp[i] + kb, an + alo[i]);
      #pragma unroll
      for (int i = 0; i < CB; ++i) async_copy16(bgp[i] + kb, bnx + blo[i]);
    }
    const bf16_t* as = As[ki & 1];
    const bf16_t* bs = Bs[ki & 1];
    #pragma unroll
    for (int kk = 0; kk < 2; ++kk) {
      bf16x8 af[MT], bf[NT];
      #pragma unroll
      for (int mt = 0; mt < MT; ++mt) {
        int row = wm + mt * 16 + c;
        int slot = (kk * 4 + quad) ^ (row & 7);
        af[mt] = *(const bf16x8*)(as + (size_t)(row * 8 + slot) * 8);
      }
      #pragma unroll
      for (int nt = 0; nt < NT; ++nt) {
        int row = wn + nt * 16 + c;
        int slot = (kk * 4 + quad) ^ (row & 7);
        bf[nt] = *(const bf16x8*)(bs + (size_t)(row * 8 + slot) * 8);
      }
      #pragma unroll
      for (int mt = 0; mt < MT; ++mt)
        #pragma unroll
        for (int nt = 0; nt < NT; ++nt)
          acc[mt][nt] = __builtin_amdgcn_mfma_f32_16x16x32_bf16(
              af[mt], bf[nt], acc[mt][nt], 0, 0, 0);
    }
  }

  bool do_vt = WRITE_VT && (bn >= 2 * HID);
  bf16_t* tb = (bf16_t*)As[0];   // reuse As for V^T staging: 2*64*72*2B < 32KB
  if (do_vt) __syncthreads();    // last tile's ds_reads done before As reuse

  #pragma unroll
  for (int nt = 0; nt < NT; ++nt) {
    int col = bn + wn + nt * 16 + c;
    float bv = bias[col];
    float sc = (SCALEQ && col < HID) ? ATT_SCALE2 : 1.0f;
    #pragma unroll
    for (int mt = 0; mt < MT; ++mt) {
      #pragma unroll
      for (int r = 0; r < 4; ++r) {
        int loc = wm + mt * 16 + quad * 4 + r;        // row within tile
        int row = bm + loc;                           // C layout: row=(lane>>4)*4+reg
        float v = (acc[mt][nt][r] + bv) * sc;
        if (OUT_BF16)
          ((bf16_t*)Cout)[(size_t)row * Nn + col] = (bf16_t)v;
        else
          ((float*)Cout)[(size_t)row * Nn + col] = v;
        if (do_vt) {
          int d = wn + nt * 16 + c;                   // col within head (BN=64)
          tb[(loc & 1) * 4608 + d * 72 + (loc >> 1)] = (bf16_t)v;
        }
      }
    }
  }

  if (do_vt) {
    __syncthreads();
    int h = (bn - 2 * HID) >> 6;
    int n2 = (tid & 7) * 8;
    #pragma unroll
    for (int i = 0; i < 2; ++i) {        // batch b
      #pragma unroll
      for (int k = 0; k < 2; ++k) {
        int d = (tid >> 3) + k * 32;
        bf16x8 vv = *(const bf16x8*)(tb + i * 4608 + d * 72 + n2);
        *(bf16x8*)(Vt + (size_t)((i * 16 + h) * HDIM + d) * N_SEQ + bm / 2 + n2) = vv;
      }
    }
  }
}

// ---------------- flash attention (unchanged) ------------------------------
__global__ __launch_bounds__(512, 4) void flash_attn_kernel(
    const bf16_t* __restrict__ Pj, const bf16_t* __restrict__ Vt,
    bf16_t* __restrict__ AO) {
  __shared__ __align__(16) bf16_t Ks[2][64 * 64];   // [j][d] swizzled
  __shared__ __align__(16) bf16_t Vs[2][64 * 64];   // [d][j] swizzled
  __shared__ __align__(16) bf16_t Ps[8][16 * 64];   // per-wave P[i][j] swizzled
  const int PJP = 3 * HID;
  int tid = threadIdx.x, wave = tid >> 6, lane = tid & 63;
  int c = lane & 15, quad = lane >> 4;
  int c7 = c & 7;
  int bid = blockIdx.x;
  int qb = (bid < 256) ? (15 - (bid >> 5)) : ((bid - 256) >> 5);
  int bh = bid & 31;
  int h = bh & 15, b = bh >> 4;
  int i0 = qb * 128;

  int i_row = i0 + wave * 16 + c;
  const bf16_t* qg = Pj + (size_t)(i_row * BATCH + b) * PJP + h * HDIM + quad * 8;
  bf16x8 qf0 = *(const bf16x8*)(qg);
  bf16x8 qf1 = *(const bf16x8*)(qg + 32);

  f32x4 o[4] = {};                   // O^T: rows d, col i=c
  float lrow = 0.f;

  int jr = tid >> 3, oc = tid & 7;
  int lds_off = jr * 64 + (oc ^ (jr & 7)) * 8;
  const bf16_t* kg0 = Pj + (size_t)b * PJP + HID + h * HDIM + oc * 8;
  const bf16_t* vg0 = Vt + (size_t)(bh * HDIM + jr) * N_SEQ + oc * 8;

  int njt = 2 * qb + 2;
  bf16x8 kreg = *(const bf16x8*)(kg0 + (size_t)jr * BATCH * PJP);
  bf16x8 vreg = *(const bf16x8*)(vg0);

  for (int jt = 0; jt < njt; ++jt) {
    bf16_t* ks = Ks[jt & 1];
    bf16_t* vs = Vs[jt & 1];
    *(bf16x8*)(ks + lds_off) = kreg;
    *(bf16x8*)(vs + lds_off) = vreg;
    __syncthreads();
    if (jt + 1 < njt) {
      int j0n = (jt + 1) * 64;
      kreg = *(const bf16x8*)(kg0 + (size_t)(j0n + jr) * BATCH * PJP);
      vreg = *(const bf16x8*)(vg0 + j0n);
    }

    f32x4 st[4];
    #pragma unroll
    for (int mt = 0; mt < 4; ++mt) {
      const bf16_t* kr = ks + (mt * 16 + c) * 64;
      bf16x8 ka0 = *(const bf16x8*)(kr + ((quad) ^ c7) * 8);
      bf16x8 ka1 = *(const bf16x8*)(kr + ((quad + 4) ^ c7) * 8);
      f32x4 s = {};
      s = __builtin_amdgcn_mfma_f32_16x16x32_bf16(ka0, qf0, s, 0, 0, 0);
      st[mt] = __builtin_amdgcn_mfma_f32_16x16x32_bf16(ka1, qf1, s, 0, 0, 0);
    }
    if (jt >= 2 * qb) {
      int j0 = jt * 64;
      int ig = i0 + wave * 16 + c;
      #pragma unroll
      for (int mt = 0; mt < 4; ++mt)
        #pragma unroll
        for (int r = 0; r < 4; ++r)
          if (j0 + mt * 16 + quad * 4 + r > ig) st[mt][r] = -1e30f;
    }

    #pragma unroll
    for (int mt = 0; mt < 4; ++mt)
      #pragma unroll
      for (int r = 0; r < 4; ++r) {
        st[mt][r] = EXP2F(st[mt][r]);
        lrow += st[mt][r];
      }

    bf16_t* pw = Ps[wave];
    #pragma unroll
    for (int mt = 0; mt < 4; ++mt) {
      bf16x4 pv;
      #pragma unroll
      for (int r = 0; r < 4; ++r) pv[r] = (bf16_t)st[mt][r];
      int joct = mt * 2 + (quad >> 1);
      *(bf16x4*)(pw + c * 64 + (joct ^ c7) * 8 + (quad & 1) * 4) = pv;
    }
    const bf16_t* pr = pw + c * 64;
    bf16x8 pa0 = *(const bf16x8*)(pr + ((quad) ^ c7) * 8);
    bf16x8 pa1 = *(const bf16x8*)(pr + ((quad + 4) ^ c7) * 8);

    #pragma unroll
    for (int nt = 0; nt < 4; ++nt) {
      const bf16_t* vr = vs + (nt * 16 + c) * 64;
      bf16x8 vb0 = *(const bf16x8*)(vr + ((quad) ^ c7) * 8);
      bf16x8 vb1 = *(const bf16x8*)(vr + ((quad + 4) ^ c7) * 8);
      o[nt] = __builtin_amdgcn_mfma_f32_16x16x32_bf16(vb0, pa0, o[nt], 0, 0, 0);
      o[nt] = __builtin_amdgcn_mfma_f32_16x16x32_bf16(vb1, pa1, o[nt], 0, 0, 0);
    }
  }

  float lfull = lrow;
  lfull += __shfl_xor(lfull, 16);
  lfull += __shfl_xor(lfull, 32);
  float linv = 1.0f / lfull;
  int orow = (i0 + wave * 16 + c) * BATCH + b;
  #pragma unroll
  for (int nt = 0; nt < 4; ++nt) {
    bf16x4 pv;
    #pragma unroll
    for (int r = 0; r < 4; ++r) pv[r] = (bf16_t)(o[nt][r] * linv);
    *(bf16x4*)(AO + (size_t)orow * HID + h * HDIM + nt * 16 + quad * 4) = pv;
  }
}

extern "C" void kernel_launch(void* const* d_in, const int* in_sizes, int n_in,
                              void* d_out, int out_size, void* d_ws, size_t ws_size,
                              hipStream_t stream) {
  const float* x      = (const float*)d_in[0];   // [2048][2][1024]
  const float* W_proj = (const float*)d_in[1];   // [1024][3072]
  const float* b_proj = (const float*)d_in[2];   // [3072]
  const float* W_out  = (const float*)d_in[3];   // [1024][1024]
  const float* b_out  = (const float*)d_in[4];   // [1024]

  bf16_t* Xb  = (bf16_t*)d_ws;                               // 4096*1024
  bf16_t* Wpt = Xb  + (size_t)NBROW * EMB;                   // 3072*1024
  bf16_t* Wot = Wpt + (size_t)3 * HID * EMB;                 // 1024*1024
  bf16_t* Pj  = Wot + (size_t)HID * EMB;                     // 4096*3072
  bf16_t* AO  = Pj  + (size_t)NBROW * 3 * HID;               // 4096*1024
  bf16_t* Vt  = AO  + (size_t)NBROW * HID;                   // 32*64*2048

  prep_kernel<<<8192, 256, 0, stream>>>(x, W_proj, W_out, Xb, Wpt, Wot);
  gemm_bt_kernel<128, 64, true, true, true>
      <<<dim3(NBROW / 128, 3 * HID / 64), 256, 0, stream>>>(
      Xb, Wpt, b_proj, (void*)Pj, Vt, NBROW, 3 * HID, EMB);
  flash_attn_kernel<<<512, 512, 0, stream>>>(Pj, Vt, AO);
  gemm_bt_kernel<128, 64, false, false, false>
      <<<dim3(NBROW / 128, EMB / 64), 256, 0, stream>>>(
      AO, Wot, b_out, d_out, nullptr, NBROW, EMB, HID);
}